// Round 1
// baseline (381.862 us; speedup 1.0000x reference)
//
#include <hip/hip_runtime.h>
#include <cmath>

#define HID 128

typedef __attribute__((ext_vector_type(8))) short bf16x8;
typedef __attribute__((ext_vector_type(16))) float f32x16;
typedef __attribute__((ext_vector_type(4))) float f32x4;

__device__ __forceinline__ unsigned rne_bf16_bits(float f) {
    unsigned u = __builtin_bit_cast(unsigned, f);
    return (u + 0x7FFFu + ((u >> 16) & 1u)) & 0xFFFF0000u;
}

__device__ __forceinline__ float fast_tanh(float x) {
    // tanh(x) = 1 - 2/(e^{2x}+1); saturates correctly at +-inf
    float e = __expf(2.0f * x);
    return 1.0f - 2.0f * __builtin_amdgcn_rcpf(e + 1.0f);
}

// ---------------------------------------------------------------------------
// Pass A: u[i] = w_score . tanh(W_proj @ x_i + b_proj)
// Block = 256 thr (4 waves). Wave = 32 rows x 128 cols via mfma 32x32x16 bf16.
// bf16x3 split (hi+lo) for ~fp32 precision. W hi/lo staged in LDS with
// XOR-swizzled 16B blocks (T2) to kill the 32-way column-read conflict.
// A-fragments loaded directly from global (each element read exactly once).
// ---------------------------------------------------------------------------
__global__ __launch_bounds__(256) void compute_u_kernel(
    const float* __restrict__ X, const float* __restrict__ W,
    const float* __restrict__ bproj, const float* __restrict__ wscore,
    float* __restrict__ u, int N)
{
    __shared__ __align__(16) short whi[128 * 128];
    __shared__ __align__(16) short wlo[128 * 128];

    const int tid = threadIdx.x;

    // Stage W (row j = output col, k contiguous) as bf16 hi/lo, swizzled.
    #pragma unroll
    for (int p = 0; p < 8; ++p) {
        int id = p * 256 + tid;        // 0..2047
        int j  = id >> 4;              // W row (output column) 0..127
        int c  = id & 15;              // 16B block within row (8 k's)
        const float* src = W + j * HID + c * 8;
        f32x4 s0 = *(const f32x4*)(src);
        f32x4 s1 = *(const f32x4*)(src + 4);
        short h8[8], l8[8];
        #pragma unroll
        for (int q = 0; q < 8; ++q) {
            float f = (q < 4) ? s0[q] : s1[q - 4];
            unsigned hb = rne_bf16_bits(f);
            float hf = __builtin_bit_cast(float, hb);
            unsigned lb = rne_bf16_bits(f - hf);
            h8[q] = (short)(hb >> 16);
            l8[q] = (short)(lb >> 16);
        }
        int dst = j * HID + ((c ^ (j & 7)) << 3);   // short index, 16B aligned
        *(bf16x8*)(&whi[dst]) = *(const bf16x8*)h8;
        *(bf16x8*)(&wlo[dst]) = *(const bf16x8*)l8;
    }
    __syncthreads();

    const int lane = tid & 63;
    const int wv   = tid >> 6;
    const int l31  = lane & 31;
    const int hig  = lane >> 5;

    const long rowBase = (long)blockIdx.x * 128 + wv * 32;
    int row  = (int)rowBase + l31;
    int rowc = (row < N) ? row : (N - 1);     // clamp loads; writes guarded
    const float* xrow = X + (size_t)rowc * HID;

    f32x16 acc[4];
    #pragma unroll
    for (int t = 0; t < 4; ++t)
        #pragma unroll
        for (int g = 0; g < 16; ++g) acc[t][g] = 0.0f;

    #pragma unroll
    for (int kc = 0; kc < 8; ++kc) {          // K chunks of 16
        int k0 = kc * 16 + hig * 8;
        f32x4 a0 = *(const f32x4*)(xrow + k0);
        f32x4 a1 = *(const f32x4*)(xrow + k0 + 4);
        short ah[8], al[8];
        #pragma unroll
        for (int q = 0; q < 8; ++q) {
            float f = (q < 4) ? a0[q] : a1[q - 4];
            unsigned hb = rne_bf16_bits(f);
            float hf = __builtin_bit_cast(float, hb);
            unsigned lb = rne_bf16_bits(f - hf);
            ah[q] = (short)(hb >> 16);
            al[q] = (short)(lb >> 16);
        }
        bf16x8 vahi = *(const bf16x8*)ah;
        bf16x8 valo = *(const bf16x8*)al;
        int cblk = kc * 2 + hig;              // 16B block index 0..15
        #pragma unroll
        for (int t = 0; t < 4; ++t) {
            int j = t * 32 + l31;
            int off = j * HID + ((cblk ^ (j & 7)) << 3);
            bf16x8 bh = *(const bf16x8*)(&whi[off]);
            bf16x8 bl = *(const bf16x8*)(&wlo[off]);
            acc[t] = __builtin_amdgcn_mfma_f32_32x32x16_bf16(vahi, bh, acc[t], 0, 0, 0);
            acc[t] = __builtin_amdgcn_mfma_f32_32x32x16_bf16(valo, bh, acc[t], 0, 0, 0);
            acc[t] = __builtin_amdgcn_mfma_f32_32x32x16_bf16(vahi, bl, acc[t], 0, 0, 0);
        }
    }

    // Epilogue: h = tanh(v + b); partial u = sum_j h*w; reduce over 32 lanes.
    float bp[4], wsr[4];
    #pragma unroll
    for (int t = 0; t < 4; ++t) {
        int j = t * 32 + l31;
        bp[t]  = bproj[j];
        wsr[t] = wscore[j];
    }

    #pragma unroll
    for (int g = 0; g < 16; ++g) {
        float s = 0.0f;
        #pragma unroll
        for (int t = 0; t < 4; ++t) {
            float h = fast_tanh(acc[t][g] + bp[t]);
            s = fmaf(h, wsr[t], s);
        }
        // butterfly sum within the 32-lane half (rows differ by lane>>5 only)
        #pragma unroll
        for (int m = 16; m > 0; m >>= 1) s += __shfl_xor(s, m, 64);
        if (l31 == 0) {
            int r = (int)rowBase + (g & 3) + 8 * (g >> 2) + 4 * hig;
            if (r < N) u[r] = s;   // b_score omitted: cancels in softmax
        }
    }
}

// ---------------------------------------------------------------------------
// Pass B: segment starts from sorted owners. seg_start[s] = first i with
// owners[i] >= s, seg_start[S] = N. Handles int32 or int64 owners storage.
// ---------------------------------------------------------------------------
__global__ void seg_start_kernel(const int* __restrict__ ow,
                                 int* __restrict__ seg_start, int N, int S)
{
    // int64 detection: little-endian high word of last elem is 0;
    // as int32 the last (max, sorted) owner is ~S-1 != 0.
    const int is64 = (ow[(size_t)N - 1] == 0) ? 1 : 0;
    long i = (long)blockIdx.x * blockDim.x + threadIdx.x;
    if (i > N) return;
    int a = (i == 0) ? -1 : ow[is64 ? (size_t)(2 * (i - 1)) : (size_t)(i - 1)];
    int b = (i == N) ? S  : ow[is64 ? (size_t)(2 * i)       : (size_t)i];
    for (int s = a + 1; s <= b; ++s) seg_start[s] = (int)i;
}

// ---------------------------------------------------------------------------
// Pass C: per-segment softmax + weighted sum of seg_embs. Block = 1 segment.
// ---------------------------------------------------------------------------
__global__ __launch_bounds__(256) void segment_agg_kernel(
    const float* __restrict__ X, const float* __restrict__ u,
    const int* __restrict__ seg_start, float* __restrict__ z)
{
    const int s = blockIdx.x;
    const int t = threadIdx.x;
    const int start = seg_start[s];
    const int end   = seg_start[s + 1];

    __shared__ float red[256];

    // 1. segment max
    float m = -INFINITY;
    for (int r = start + t; r < end; r += 256) m = fmaxf(m, u[r]);
    red[t] = m; __syncthreads();
    #pragma unroll
    for (int o = 128; o > 0; o >>= 1) {
        if (t < o) red[t] = fmaxf(red[t], red[t + o]);
        __syncthreads();
    }
    const float umax = red[0];
    __syncthreads();

    // 2. denominator
    float sum = 0.0f;
    for (int r = start + t; r < end; r += 256) sum += __expf(u[r] - umax);
    red[t] = sum; __syncthreads();
    #pragma unroll
    for (int o = 128; o > 0; o >>= 1) {
        if (t < o) red[t] += red[t + o];
        __syncthreads();
    }
    const float inv = (end > start) ? (1.0f / red[0]) : 0.0f;
    __syncthreads();

    // 3. weighted accumulation: 2 row-lanes x 128 cols
    const int c  = t & 127;
    const int h2 = t >> 7;
    float acc = 0.0f;
    for (int r = start + h2; r < end; r += 2) {
        float w = __expf(u[r] - umax) * inv;
        acc = fmaf(w, X[(size_t)r * HID + c], acc);
    }
    red[t] = acc; __syncthreads();
    if (t < 128) z[(size_t)s * HID + t] = red[t] + red[t + 128];
}

// ---------------------------------------------------------------------------
extern "C" void kernel_launch(void* const* d_in, const int* in_sizes, int n_in,
                              void* d_out, int out_size, void* d_ws, size_t ws_size,
                              hipStream_t stream)
{
    const float* X   = (const float*)d_in[0];
    const int*   ow  = (const int*)  d_in[1];
    const float* W   = (const float*)d_in[2];
    const float* bp  = (const float*)d_in[3];
    const float* wsc = (const float*)d_in[4];

    const int N = in_sizes[0] / HID;
    const int S = out_size / HID;

    float* u  = (float*)d_ws;
    int* seg  = (int*)((char*)d_ws + (((size_t)N * 4 + 255) & ~(size_t)255));
    float* z  = (float*)d_out;

    const int blocksA = (N + 127) / 128;
    compute_u_kernel<<<blocksA, 256, 0, stream>>>(X, W, bp, wsc, u, N);

    const int blocksB = (N + 1 + 255) / 256;
    seg_start_kernel<<<blocksB, 256, 0, stream>>>(ow, seg, N, S);

    segment_agg_kernel<<<S, 256, 0, stream>>>(X, u, seg, z);
}

// Round 2
// 280.849 us; speedup vs baseline: 1.3597x; 1.3597x over previous
//
#include <hip/hip_runtime.h>
#include <cmath>

#define HID 128

typedef __attribute__((ext_vector_type(8))) short bf16x8;
typedef __attribute__((ext_vector_type(16))) float f32x16;
typedef __attribute__((ext_vector_type(4))) float f32x4;
typedef __attribute__((ext_vector_type(4))) unsigned u32x4;

__device__ __forceinline__ unsigned rne_bf16_bits(float f) {
    unsigned u = __builtin_bit_cast(unsigned, f);
    return (u + 0x7FFFu + ((u >> 16) & 1u)) & 0xFFFF0000u;
}

__device__ __forceinline__ float fast_tanh(float x) {
    float e = __expf(2.0f * x);
    return 1.0f - 2.0f * __builtin_amdgcn_rcpf(e + 1.0f);
}

// Truncation split of 8 floats into bf16 hi + lo. hi = top 16 bits (trunc);
// lo = trunc16(f - hi). hi+lo == f to ~2^-16 relative, so hi needs no RNE.
__device__ __forceinline__ void split8(const float* f, bf16x8& hi, bf16x8& lo) {
    u32x4 h, l;
    #pragma unroll
    for (int p = 0; p < 4; ++p) {
        unsigned u0 = __builtin_bit_cast(unsigned, f[2 * p]);
        unsigned u1 = __builtin_bit_cast(unsigned, f[2 * p + 1]);
        h[p] = (u0 >> 16) | (u1 & 0xFFFF0000u);
        float hf0 = __builtin_bit_cast(float, u0 & 0xFFFF0000u);
        float hf1 = __builtin_bit_cast(float, u1 & 0xFFFF0000u);
        unsigned d0 = __builtin_bit_cast(unsigned, f[2 * p] - hf0);
        unsigned d1 = __builtin_bit_cast(unsigned, f[2 * p + 1] - hf1);
        l[p] = (d0 >> 16) | (d1 & 0xFFFF0000u);
    }
    hi = __builtin_bit_cast(bf16x8, h);
    lo = __builtin_bit_cast(bf16x8, l);
}

// ---------------------------------------------------------------------------
// Prep: W (f32, row j = output col, k contiguous) -> bf16 RNE hi, stored
// pre-swizzled (16B block c of row j lands at c^(j&7)) so compute_u can
// stage it into LDS with a linear copy. 2048 threads, one 16B block each.
// ---------------------------------------------------------------------------
__global__ __launch_bounds__(256) void prep_w_kernel(
    const float* __restrict__ W, short* __restrict__ whi)
{
    int id = blockIdx.x * 256 + threadIdx.x;   // 0..2047
    int j = id >> 4;                           // W row (output column)
    int c = id & 15;                           // 16B block (8 k's)
    const float* src = W + j * HID + c * 8;
    short h8[8];
    #pragma unroll
    for (int q = 0; q < 8; ++q)
        h8[q] = (short)(rne_bf16_bits(src[q]) >> 16);
    *(bf16x8*)(&whi[j * HID + ((c ^ (j & 7)) << 3)]) = *(const bf16x8*)h8;
}

// ---------------------------------------------------------------------------
// Pass A: u[i] = w_score . tanh(W_proj @ x_i + b_proj)
// Block = 256 thr (4 waves). Wave = 32 rows x 128 cols via mfma 32x32x16 bf16.
// 2-term split (Ahi.Bhi + Alo.Bhi), B = W-hi only (32 KB LDS, swizzled).
// ---------------------------------------------------------------------------
__global__ __launch_bounds__(256) void compute_u_kernel(
    const float* __restrict__ X, const short* __restrict__ whi_g,
    const float* __restrict__ bproj, const float* __restrict__ wscore,
    float* __restrict__ u, int N)
{
    __shared__ __align__(16) short whi[128 * 128];

    const int tid = threadIdx.x;

    // Stage pre-swizzled W-hi: linear 32 KB copy (L2-hot source).
    #pragma unroll
    for (int it = 0; it < 8; ++it) {
        int idx = (it * 256 + tid) * 8;
        *(bf16x8*)(&whi[idx]) = *(const bf16x8*)(&whi_g[idx]);
    }
    __syncthreads();

    const int lane = tid & 63;
    const int wv   = tid >> 6;
    const int l31  = lane & 31;
    const int hig  = lane >> 5;

    const long rowBase = (long)blockIdx.x * 128 + wv * 32;
    int row  = (int)rowBase + l31;
    int rowc = (row < N) ? row : (N - 1);     // clamp loads; writes guarded
    const float* xrow = X + (size_t)rowc * HID;

    f32x16 acc[4];
    #pragma unroll
    for (int t = 0; t < 4; ++t)
        #pragma unroll
        for (int g = 0; g < 16; ++g) acc[t][g] = 0.0f;

    #pragma unroll
    for (int kc = 0; kc < 8; ++kc) {          // K chunks of 16
        int k0 = kc * 16 + hig * 8;
        float a8[8];
        *(f32x4*)(a8)     = *(const f32x4*)(xrow + k0);
        *(f32x4*)(a8 + 4) = *(const f32x4*)(xrow + k0 + 4);
        bf16x8 vahi, valo;
        split8(a8, vahi, valo);
        int cblk = kc * 2 + hig;              // 16B block index 0..15
        #pragma unroll
        for (int t = 0; t < 4; ++t) {
            int j = t * 32 + l31;
            int off = j * HID + ((cblk ^ (j & 7)) << 3);
            bf16x8 bh = *(const bf16x8*)(&whi[off]);
            acc[t] = __builtin_amdgcn_mfma_f32_32x32x16_bf16(vahi, bh, acc[t], 0, 0, 0);
            acc[t] = __builtin_amdgcn_mfma_f32_32x32x16_bf16(valo, bh, acc[t], 0, 0, 0);
        }
    }

    // Epilogue: h = tanh(v + b); u = sum_j h*w; butterfly over 32-lane half.
    float bp[4], wsr[4];
    #pragma unroll
    for (int t = 0; t < 4; ++t) {
        int j = t * 32 + l31;
        bp[t]  = bproj[j];
        wsr[t] = wscore[j];
    }

    #pragma unroll
    for (int g = 0; g < 16; ++g) {
        float s = 0.0f;
        #pragma unroll
        for (int t = 0; t < 4; ++t) {
            float h = fast_tanh(acc[t][g] + bp[t]);
            s = fmaf(h, wsr[t], s);
        }
        #pragma unroll
        for (int m = 16; m > 0; m >>= 1) s += __shfl_xor(s, m, 64);
        if (l31 == 0) {
            int r = (int)rowBase + (g & 3) + 8 * (g >> 2) + 4 * hig;
            if (r < N) u[r] = s;   // b_score omitted: cancels in softmax
        }
    }
}

// ---------------------------------------------------------------------------
// Pass B1: segment starts from sorted owners (int32 or int64 storage).
// ---------------------------------------------------------------------------
__global__ void seg_start_kernel(const int* __restrict__ ow,
                                 int* __restrict__ seg_start, int N, int S)
{
    const int is64 = (ow[(size_t)N - 1] == 0) ? 1 : 0;
    long i = (long)blockIdx.x * blockDim.x + threadIdx.x;
    if (i > N) return;
    int a = (i == 0) ? -1 : ow[is64 ? (size_t)(2 * (i - 1)) : (size_t)(i - 1)];
    int b = (i == N) ? S  : ow[is64 ? (size_t)(2 * i)       : (size_t)i];
    for (int s = a + 1; s <= b; ++s) seg_start[s] = (int)i;
}

// ---------------------------------------------------------------------------
// Pass B2: per-segment softmax over u, in place: u[r] <- exp(u-max)/denom.
// One wave per segment; u is only 4 MB so re-reads are L1/L2-hot.
// ---------------------------------------------------------------------------
__global__ __launch_bounds__(64) void finalize_kernel(
    float* __restrict__ u, const int* __restrict__ seg_start)
{
    const int s = blockIdx.x;
    const int start = seg_start[s];
    const int end   = seg_start[s + 1];
    const int lane  = threadIdx.x;

    float m = -INFINITY;
    for (int r = start + lane; r < end; r += 64) m = fmaxf(m, u[r]);
    #pragma unroll
    for (int o = 32; o > 0; o >>= 1) m = fmaxf(m, __shfl_xor(m, o, 64));

    float sum = 0.0f;
    for (int r = start + lane; r < end; r += 64) sum += __expf(u[r] - m);
    #pragma unroll
    for (int o = 32; o > 0; o >>= 1) sum += __shfl_xor(sum, o, 64);

    const float inv = (end > start) ? __builtin_amdgcn_rcpf(sum) : 0.0f;
    for (int r = start + lane; r < end; r += 64) u[r] = __expf(u[r] - m) * inv;
}

// ---------------------------------------------------------------------------
// Pass C: z[s] = sum_i a_i * x_i. Single-phase stream, 2 rows x 128 cols,
// 2-deep unrolled accumulators.
// ---------------------------------------------------------------------------
__global__ __launch_bounds__(256) void segment_agg_kernel(
    const float* __restrict__ X, const float* __restrict__ a,
    const int* __restrict__ seg_start, float* __restrict__ z)
{
    const int s = blockIdx.x;
    const int t = threadIdx.x;
    const int start = seg_start[s];
    const int end   = seg_start[s + 1];
    const int c  = t & 127;
    const int h2 = t >> 7;

    float acc0 = 0.0f, acc1 = 0.0f;
    int r = start + h2;
    for (; r + 2 < end; r += 4) {
        acc0 = fmaf(a[r],     X[(size_t)r * HID + c],       acc0);
        acc1 = fmaf(a[r + 2], X[(size_t)(r + 2) * HID + c], acc1);
    }
    for (; r < end; r += 2)
        acc0 = fmaf(a[r], X[(size_t)r * HID + c], acc0);

    __shared__ float red[256];
    red[t] = acc0 + acc1;
    __syncthreads();
    if (t < 128) z[(size_t)s * HID + t] = red[t] + red[t + 128];
}

// ---------------------------------------------------------------------------
extern "C" void kernel_launch(void* const* d_in, const int* in_sizes, int n_in,
                              void* d_out, int out_size, void* d_ws, size_t ws_size,
                              hipStream_t stream)
{
    const float* X   = (const float*)d_in[0];
    const int*   ow  = (const int*)  d_in[1];
    const float* W   = (const float*)d_in[2];
    const float* bp  = (const float*)d_in[3];
    const float* wsc = (const float*)d_in[4];

    const int N = in_sizes[0] / HID;
    const int S = out_size / HID;

    char* ws = (char*)d_ws;
    size_t off_u   = 0;
    size_t off_seg = ((size_t)N * 4 + 255) & ~(size_t)255;
    size_t off_w   = (off_seg + ((size_t)(S + 1) * 4) + 255) & ~(size_t)255;

    float* u   = (float*)(ws + off_u);
    int*   seg = (int*)  (ws + off_seg);
    short* whi = (short*)(ws + off_w);
    float* z   = (float*)d_out;

    prep_w_kernel<<<8, 256, 0, stream>>>(W, whi);

    const int blocksA = (N + 127) / 128;
    compute_u_kernel<<<blocksA, 256, 0, stream>>>(X, whi, bp, wsc, u, N);

    const int blocksB = ((N + 1) + 255) / 256;
    seg_start_kernel<<<blocksB, 256, 0, stream>>>(ow, seg, N, S);

    finalize_kernel<<<S, 64, 0, stream>>>(u, seg);

    segment_agg_kernel<<<S, 256, 0, stream>>>(X, u, seg, z);
}